// Round 4
// baseline (193.246 us; speedup 1.0000x reference)
//
#include <hip/hip_runtime.h>
#include <hip/hip_bf16.h>

#define T_LEN 2048
#define BSZ 4
#define EMB 256
#define HDIM 32
#define QSCALE 0.17677669529663687f
#define LOG2E 1.4426950408889634f

using bf16x8 = __attribute__((ext_vector_type(8))) short;
using bf16x4 = __attribute__((ext_vector_type(4))) short;
using f32x4 = __attribute__((ext_vector_type(4))) float;

static __device__ __forceinline__ unsigned fasu(float f) {
  union { float f; unsigned u; } c; c.f = f; return c.u;
}
// pack two floats to packed bf16 pair (round-half-up) in ONE v_perm + 2 adds
static __device__ __forceinline__ unsigned pack2r(float lo, float hi) {
  return __builtin_amdgcn_perm(fasu(hi) + 0x8000u, fasu(lo) + 0x8000u, 0x07060302u);
}
static __device__ __forceinline__ unsigned short bfr(float x) {
  return (unsigned short)((fasu(x) + 0x8000u) >> 16);
}
// build a bf16x8 MFMA fragment from 8 consecutive f32 (two float4 loads)
static __device__ __forceinline__ bf16x8 pack8(const float* __restrict__ p) {
  float4 w0 = ((const float4*)p)[0], w1 = ((const float4*)p)[1];
  union { unsigned u[4]; bf16x8 v; } f;
  f.u[0] = pack2r(w0.x, w0.y);
  f.u[1] = pack2r(w0.z, w0.w);
  f.u[2] = pack2r(w1.x, w1.y);
  f.u[3] = pack2r(w1.z, w1.w);
  return f.v;
}

// fused QKV projection: z=0 -> qh [bh][t][32], z=1 -> kh, z=2 -> vt [bh][32][t]
// R11: W consumed in f32 and packed to bf16 inline (cvt_w4 launch eliminated).
// Q scale (QSCALE*LOG2E) applied at the EPILOGUE (acc*s + b*LOG2E), exact
// algebra, hot loop unscaled. n-tile 128, grid (128,2,3) = 768 blocks = 3/CU.
__global__ __launch_bounds__(256) void qkv_proj(
    const float* __restrict__ Aq, const float* __restrict__ Ak, const float* __restrict__ Av,
    const float* __restrict__ Wq, const float* __restrict__ Wk, const float* __restrict__ Wv,
    const float* __restrict__ bq, const float* __restrict__ bk, const float* __restrict__ bv,
    unsigned short* __restrict__ qh, unsigned short* __restrict__ kh, unsigned short* __restrict__ vt) {
  __shared__ __align__(16) unsigned short smem[64 * 136];  // [m_local][n_local], stride 136 (16B-aligned rows)
  const int z = blockIdx.z;
  const float* A = z == 0 ? Aq : z == 1 ? Ak : Av;
  const float* W = z == 0 ? Wq : z == 1 ? Wk : Wv;
  const float* bias = z == 0 ? bq : z == 1 ? bk : bv;
  const float ascale = z == 0 ? QSCALE * LOG2E : 1.0f;   // applied to acc at epilogue
  const float bscale = z == 0 ? LOG2E : 1.0f;
  const int lane = threadIdx.x & 63;
  const int wave = threadIdx.x >> 6;
  const int quad = lane >> 4;
  const int l16 = lane & 15;
  const int m0b = blockIdx.x * 64;
  const int m0 = m0b + wave * 16;
  const int n0 = blockIdx.y * 128;
  f32x4 acc[8];
#pragma unroll
  for (int i = 0; i < 8; ++i) acc[i] = f32x4{0.f, 0.f, 0.f, 0.f};
  const float* arow = A + (m0 + l16) * EMB;
#pragma unroll
  for (int k0 = 0; k0 < EMB; k0 += 32) {
    bf16x8 af = pack8(arow + k0 + quad * 8);
    const float* wbase = W + k0 + quad * 8;
#pragma unroll
    for (int nt = 0; nt < 8; ++nt) {
      bf16x8 b = pack8(wbase + (n0 + nt * 16 + l16) * EMB);
      acc[nt] = __builtin_amdgcn_mfma_f32_16x16x32_bf16(af, b, acc[nt], 0, 0, 0);
    }
  }
#pragma unroll
  for (int nt = 0; nt < 8; ++nt) {
    float bn = bias[n0 + nt * 16 + l16] * bscale;
#pragma unroll
    for (int r = 0; r < 4; ++r)
      smem[(wave * 16 + quad * 4 + r) * 136 + nt * 16 + l16] = bfr(fmaf(acc[nt][r], ascale, bn));
  }
  __syncthreads();
  if (z < 2) {
    // coalesced 64B/thread stores to [bh][t][hd]; 16-col chunk stays inside one head
    int row = threadIdx.x >> 2, seg = threadIdx.x & 3;
    int m = m0b + row, t = m >> 2, b = m & 3;
#pragma unroll
    for (int c = 0; c < 2; ++c) {
      int n = n0 + seg * 32 + c * 16;
      int h = n >> 5, hd = n & 31;
      unsigned short* dst = (z == 0 ? qh : kh) + (((b << 3) + h) * T_LEN + t) * HDIM + hd;
      *(bf16x8*)(dst + 0) = *(const bf16x8*)(smem + row * 136 + seg * 32 + c * 16 + 0);
      *(bf16x8*)(dst + 8) = *(const bf16x8*)(smem + row * 136 + seg * 32 + c * 16 + 8);
    }
  } else {
    // transposed [bh][hd][t]: each thread emits 32B t-contiguous chunks, 2 columns
#pragma unroll
    for (int half = 0; half < 2; ++half) {
      int nl = half * 64 + (threadIdx.x >> 2), b = threadIdx.x & 3;
      unsigned w[8];
#pragma unroll
      for (int i = 0; i < 8; ++i) {
        unsigned lo = smem[((2 * i) * 4 + b) * 136 + nl];
        unsigned hi = smem[((2 * i + 1) * 4 + b) * 136 + nl];
        w[i] = lo | (hi << 16);
      }
      int nf = n0 + nl, h = nf >> 5, hd = nf & 31;
      int tbase = m0b >> 2;
      unsigned* base = (unsigned*)(vt + (((b << 3) + h) * HDIM + hd) * T_LEN + tbase);
      ((uint4*)base)[0] = make_uint4(w[0], w[1], w[2], w[3]);
      ((uint4*)base)[1] = make_uint4(w[4], w[5], w[6], w[7]);
    }
  }
}

// out = A @ W^T + bias ; A bf16 [8192][256], W f32 (packed inline), out fp32
__global__ __launch_bounds__(256) void out_gemm(const unsigned short* __restrict__ A,
                                                const float* __restrict__ W,
                                                const float* __restrict__ bias,
                                                float* __restrict__ out) {
  __shared__ __align__(16) float smem[64 * 68];  // stride 68 floats = 272B (16B-aligned)
  const int lane = threadIdx.x & 63;
  const int wave = threadIdx.x >> 6;
  const int quad = lane >> 4;
  const int l16 = lane & 15;
  const int m0b = blockIdx.x * 64;
  const int m0 = m0b + wave * 16;
  const int n0 = blockIdx.y * 64;
  f32x4 acc0 = {0.f, 0.f, 0.f, 0.f}, acc1 = acc0, acc2 = acc0, acc3 = acc0;
  const unsigned short* arow = A + (m0 + l16) * EMB;
#pragma unroll
  for (int k0 = 0; k0 < EMB; k0 += 32) {
    bf16x8 af = *(const bf16x8*)(arow + k0 + quad * 8);
    const float* wbase = W + k0 + quad * 8;
    bf16x8 b0 = pack8(wbase + (n0 + 0 + l16) * EMB);
    bf16x8 b1 = pack8(wbase + (n0 + 16 + l16) * EMB);
    bf16x8 b2 = pack8(wbase + (n0 + 32 + l16) * EMB);
    bf16x8 b3 = pack8(wbase + (n0 + 48 + l16) * EMB);
    acc0 = __builtin_amdgcn_mfma_f32_16x16x32_bf16(af, b0, acc0, 0, 0, 0);
    acc1 = __builtin_amdgcn_mfma_f32_16x16x32_bf16(af, b1, acc1, 0, 0, 0);
    acc2 = __builtin_amdgcn_mfma_f32_16x16x32_bf16(af, b2, acc2, 0, 0, 0);
    acc3 = __builtin_amdgcn_mfma_f32_16x16x32_bf16(af, b3, acc3, 0, 0, 0);
  }
  f32x4 accs[4] = {acc0, acc1, acc2, acc3};
#pragma unroll
  for (int nt = 0; nt < 4; ++nt) {
    float bn = bias[n0 + nt * 16 + l16];
#pragma unroll
    for (int r = 0; r < 4; ++r)
      smem[(wave * 16 + quad * 4 + r) * 68 + nt * 16 + l16] = accs[nt][r] + bn;
  }
  __syncthreads();
  int row = threadIdx.x >> 2, seg = threadIdx.x & 3;
  const float4* srcp = (const float4*)(smem + row * 68 + seg * 16);
  float4* dstp = (float4*)(out + (m0b + row) * EMB + n0 + seg * 16);
#pragma unroll
  for (int i = 0; i < 4; ++i) dstp[i] = srcp[i];
}

// Flash attention: K+V LDS-staged (double-buffered 128-key chunks), 2 Q-frags
// per wave (32 q-rows). Hot loop per 16 keys: 1 ds_read_b128 (K) + 2 ds_read_b64
// (V) -> 2x S^T=K.Q^T (16x16x32) -> 8 exp2 (log2-domain, no max) -> 4 packs ->
// 4x 16x16x16 PV MFMA; denominator on VALU (6 adds) + cross-quad shfl reduce in
// epilogue; s_setprio(1) around MFMA clusters. (R10 body, unchanged.)
__global__ __launch_bounds__(256) void flash_attn(const unsigned short* __restrict__ qh,
                                                  const unsigned short* __restrict__ kh,
                                                  const unsigned short* __restrict__ vt,
                                                  unsigned short* __restrict__ aout) {
  __shared__ __align__(16) unsigned short kbuf[2][128 * 32];      // 2 x 8 KB, flat copy of K rows
  __shared__ __align__(16) unsigned short vbuf[2][32 * 136];      // 2 x 8.5 KB, V [d][key], stride 136
  const int tid = threadIdx.x;
  const int lane = tid & 63;
  const int wave = tid >> 6;
  const int quad = lane >> 4;
  const int l16 = lane & 15;
  const int bh = blockIdx.x;
  const int q0 = blockIdx.y * 128 + wave * 32;
  const unsigned short* qs = qh + bh * (T_LEN * HDIM);
  const unsigned short* ks = kh + bh * (T_LEN * HDIM);
  const unsigned short* vs = vt + bh * (T_LEN * HDIM);
  const bf16x8 qf0 = *(const bf16x8*)(qs + (q0 + l16) * HDIM + quad * 8);
  const bf16x8 qf1 = *(const bf16x8*)(qs + (q0 + 16 + l16) * HDIM + quad * 8);
  f32x4 o00 = {0.f, 0.f, 0.f, 0.f};
  f32x4 o01 = o00, o10 = o00, o11 = o00;
  float den0 = 0.f, den1 = 0.f;
  const f32x4 zero = o00;

  const int vrow = tid >> 4;          // 0..15 (and +16 in second shot)
  const int vcol = (tid & 15) * 8;    // 16B units along keys

  // stage chunk 0
  {
    uint4 ka = *(const uint4*)(ks + tid * 8);
    uint4 kb = *(const uint4*)(ks + (tid + 256) * 8);
    uint4 va = *(const uint4*)(vs + vrow * T_LEN + vcol);
    uint4 vb = *(const uint4*)(vs + (vrow + 16) * T_LEN + vcol);
    *(uint4*)(&kbuf[0][tid * 8]) = ka;
    *(uint4*)(&kbuf[0][(tid + 256) * 8]) = kb;
    *(uint4*)(&vbuf[0][vrow * 136 + vcol]) = va;
    *(uint4*)(&vbuf[0][(vrow + 16) * 136 + vcol]) = vb;
  }
  __syncthreads();

  for (int chunk = 0; chunk < 16; ++chunk) {
    const int buf = chunk & 1;
    uint4 ka, kb, va, vb;
    const bool pf = (chunk + 1) < 16;
    if (pf) {
      const int kk0 = (chunk + 1) * 128;
      const unsigned short* kg = ks + kk0 * HDIM;
      ka = *(const uint4*)(kg + tid * 8);
      kb = *(const uint4*)(kg + (tid + 256) * 8);
      va = *(const uint4*)(vs + vrow * T_LEN + kk0 + vcol);
      vb = *(const uint4*)(vs + (vrow + 16) * T_LEN + kk0 + vcol);
    }
#pragma unroll
    for (int it = 0; it < 8; ++it) {
      const int kkl = it * 16;
      bf16x8 kf = *(const bf16x8*)(&kbuf[buf][(kkl + l16) * 32 + quad * 8]);
      bf16x4 vfa = *(const bf16x4*)(&vbuf[buf][l16 * 136 + kkl + quad * 4]);
      bf16x4 vfb = *(const bf16x4*)(&vbuf[buf][(l16 + 16) * 136 + kkl + quad * 4]);
      __builtin_amdgcn_s_setprio(1);
      f32x4 s0 = __builtin_amdgcn_mfma_f32_16x16x32_bf16(kf, qf0, zero, 0, 0, 0);
      f32x4 s1 = __builtin_amdgcn_mfma_f32_16x16x32_bf16(kf, qf1, zero, 0, 0, 0);
      __builtin_amdgcn_s_setprio(0);
      union { unsigned u[2]; bf16x4 v; } pp0, pp1;
      {
        float a = __builtin_amdgcn_exp2f(s0[0]), b = __builtin_amdgcn_exp2f(s0[1]);
        float c = __builtin_amdgcn_exp2f(s0[2]), d = __builtin_amdgcn_exp2f(s0[3]);
        pp0.u[0] = pack2r(a, b); pp0.u[1] = pack2r(c, d);
        den0 += (a + b) + (c + d);
        a = __builtin_amdgcn_exp2f(s1[0]); b = __builtin_amdgcn_exp2f(s1[1]);
        c = __builtin_amdgcn_exp2f(s1[2]); d = __builtin_amdgcn_exp2f(s1[3]);
        pp1.u[0] = pack2r(a, b); pp1.u[1] = pack2r(c, d);
        den1 += (a + b) + (c + d);
      }
      __builtin_amdgcn_s_setprio(1);
      o00 = __builtin_amdgcn_mfma_f32_16x16x16bf16_1k(vfa, pp0.v, o00, 0, 0, 0);
      o01 = __builtin_amdgcn_mfma_f32_16x16x16bf16_1k(vfb, pp0.v, o01, 0, 0, 0);
      o10 = __builtin_amdgcn_mfma_f32_16x16x16bf16_1k(vfa, pp1.v, o10, 0, 0, 0);
      o11 = __builtin_amdgcn_mfma_f32_16x16x16bf16_1k(vfb, pp1.v, o11, 0, 0, 0);
      __builtin_amdgcn_s_setprio(0);
    }
    if (pf) {
      const int nb = buf ^ 1;
      *(uint4*)(&kbuf[nb][tid * 8]) = ka;
      *(uint4*)(&kbuf[nb][(tid + 256) * 8]) = kb;
      *(uint4*)(&vbuf[nb][vrow * 136 + vcol]) = va;
      *(uint4*)(&vbuf[nb][(vrow + 16) * 136 + vcol]) = vb;
    }
    __syncthreads();
  }

  // denominator: per-lane partial covers k = quad*4+{0..3} slices; full sum for
  // q=l16 is the reduction over the 4 quads (lane bits 4,5)
  float d0 = den0; d0 += __shfl_xor(d0, 16); d0 += __shfl_xor(d0, 32);
  float d1 = den1; d1 += __shfl_xor(d1, 16); d1 += __shfl_xor(d1, 32);

  // epilogue: normalize + O^T (C-layout: d=quad*4+r, q=l16) -> row-major [q][d]
  const int srcA = l16 + ((quad & 1) << 5);
  const int srcB = srcA + 16;
  const bool lowq = quad < 2;
  const int b = bh >> 3, h = bh & 7;
#pragma unroll
  for (int f = 0; f < 2; ++f) {
    f32x4 oh0 = f == 0 ? o00 : o10;
    f32x4 oh1 = f == 0 ? o01 : o11;
    const float inv = 1.f / (f == 0 ? d0 : d1);
    unsigned oa = pack2r(oh0[0] * inv, oh0[1] * inv), ob = pack2r(oh0[2] * inv, oh0[3] * inv);
    unsigned oc = pack2r(oh1[0] * inv, oh1[1] * inv), od = pack2r(oh1[2] * inv, oh1[3] * inv);
    union { unsigned u[4]; bf16x8 v; } of;
    unsigned ta, tc;
    ta = __shfl(oa, srcA); tc = __shfl(oc, srcA); of.u[0] = lowq ? ta : tc;
    ta = __shfl(ob, srcA); tc = __shfl(od, srcA); of.u[1] = lowq ? ta : tc;
    ta = __shfl(oa, srcB); tc = __shfl(oc, srcB); of.u[2] = lowq ? ta : tc;
    ta = __shfl(ob, srcB); tc = __shfl(od, srcB); of.u[3] = lowq ? ta : tc;
    const int t = q0 + f * 16 + l16;
    *(bf16x8*)(aout + (t * BSZ + b) * EMB + h * HDIM + quad * 8) = of.v;
  }
}

extern "C" void kernel_launch(void* const* d_in, const int* in_sizes, int n_in,
                              void* d_out, int out_size, void* d_ws, size_t ws_size,
                              hipStream_t stream) {
  const float* q  = (const float*)d_in[0];
  const float* k  = (const float*)d_in[1];
  const float* v  = (const float*)d_in[2];
  const float* Wq = (const float*)d_in[3];
  const float* bq = (const float*)d_in[4];
  const float* Wk = (const float*)d_in[5];
  const float* bk = (const float*)d_in[6];
  const float* Wv = (const float*)d_in[7];
  const float* bv = (const float*)d_in[8];
  const float* Wp = (const float*)d_in[9];
  const float* bp = (const float*)d_in[10];
  float* out = (float*)d_out;

  char* ws = (char*)d_ws;
  unsigned short* qh   = (unsigned short*)(ws);                    // 4 MiB
  unsigned short* kh   = (unsigned short*)(ws + (4u << 20));       // 4 MiB
  unsigned short* vt   = (unsigned short*)(ws + (8u << 20));       // 4 MiB
  unsigned short* aout = (unsigned short*)(ws + (12u << 20));      // 4 MiB

  qkv_proj<<<dim3(128, 2, 3), 256, 0, stream>>>(q, k, v, Wq, Wk, Wv, bq, bk, bv, qh, kh, vt);
  flash_attn<<<dim3(32, 16), 256, 0, stream>>>(qh, kh, vt, aout);
  out_gemm<<<dim3(128, 4), 256, 0, stream>>>(aout, Wp, bp, out);
}

// Round 5
// 145.835 us; speedup vs baseline: 1.3251x; 1.3251x over previous
//
#include <hip/hip_runtime.h>
#include <hip/hip_bf16.h>

#define T_LEN 2048
#define BSZ 4
#define EMB 256
#define HDIM 32
#define QSCALE 0.17677669529663687f
#define LOG2E 1.4426950408889634f

using bf16x8 = __attribute__((ext_vector_type(8))) short;
using bf16x4 = __attribute__((ext_vector_type(4))) short;
using f32x4 = __attribute__((ext_vector_type(4))) float;

static __device__ __forceinline__ unsigned fasu(float f) {
  union { float f; unsigned u; } c; c.f = f; return c.u;
}
// pack two floats to packed bf16 pair (round-half-up) in ONE v_perm + 2 adds
static __device__ __forceinline__ unsigned pack2r(float lo, float hi) {
  return __builtin_amdgcn_perm(fasu(hi) + 0x8000u, fasu(lo) + 0x8000u, 0x07060302u);
}
static __device__ __forceinline__ unsigned short bfr(float x) {
  return (unsigned short)((fasu(x) + 0x8000u) >> 16);
}
// build a bf16x8 MFMA fragment from 8 consecutive f32 (two float4 loads)
static __device__ __forceinline__ bf16x8 pack8(const float* __restrict__ p) {
  float4 w0 = ((const float4*)p)[0], w1 = ((const float4*)p)[1];
  union { unsigned u[4]; bf16x8 v; } f;
  f.u[0] = pack2r(w0.x, w0.y);
  f.u[1] = pack2r(w0.z, w0.w);
  f.u[2] = pack2r(w1.x, w1.y);
  f.u[3] = pack2r(w1.z, w1.w);
  return f.v;
}

// ---- cooperative W-tile stage: 64 rows x 256 k of f32 W -> swizzled bf16 LDS ----
// thread t: row r=t>>2, lane-quarter q4=t&3 covers k = q4*8 + c*32 (c=0..7).
// chunk index (16B units along k) = c*4+q4; stored at chunk^(r&7) -> 2-way max
// bank pattern on write AND on the hot-loop ds_read_b128 (free, m136).
static __device__ __forceinline__ void stage_w(unsigned short* __restrict__ lds,
                                               const float* __restrict__ W,
                                               int n0, float wscale, int tid) {
  const int r = tid >> 2, q4 = tid & 3;
  const float* wr = W + (n0 + r) * EMB + q4 * 8;
#pragma unroll
  for (int c = 0; c < 8; ++c) {
    float4 f0 = ((const float4*)(wr + c * 32))[0];
    float4 f1 = ((const float4*)(wr + c * 32))[1];
    union { unsigned u[4]; uint4 v; } pk;
    pk.u[0] = pack2r(f0.x * wscale, f0.y * wscale);
    pk.u[1] = pack2r(f0.z * wscale, f0.w * wscale);
    pk.u[2] = pack2r(f1.x * wscale, f1.y * wscale);
    pk.u[3] = pack2r(f1.z * wscale, f1.w * wscale);
    const int chunk = c * 4 + q4;
    *(uint4*)&lds[r * 256 + ((chunk ^ (r & 7)) << 3)] = pk.v;
  }
}
// swizzled fragment read: row, k0 (multiple of 32), quad
static __device__ __forceinline__ bf16x8 read_w(const unsigned short* __restrict__ lds,
                                                int row, int k0, int quad) {
  const int chunk = (k0 >> 3) + quad;
  return *(const bf16x8*)&lds[row * 256 + ((chunk ^ (row & 7)) << 3)];
}

// fused QKV projection: z=0 -> qh [bh][t][32], z=1 -> kh, z=2 -> vt [bh][32][t]
// R12: W staged in LDS (was: every wave re-fetched scattered W rows from global
// every k-iter -> 18 VMEM/iter, latency-bound, 58us measured). Now: coalesced
// one-time stage + 4 ds_read_b128/iter + 2 VMEM/iter (A only). Q scale folded
// into W pre-rounding. LDS buffer (32KB) reused for the output stage.
__global__ __launch_bounds__(256) void qkv_proj(
    const float* __restrict__ Aq, const float* __restrict__ Ak, const float* __restrict__ Av,
    const float* __restrict__ Wq, const float* __restrict__ Wk, const float* __restrict__ Wv,
    const float* __restrict__ bq, const float* __restrict__ bk, const float* __restrict__ bv,
    unsigned short* __restrict__ qh, unsigned short* __restrict__ kh, unsigned short* __restrict__ vt) {
  __shared__ __align__(16) unsigned short lds[64 * 256];   // 32 KB: W-tile, then out-stage
  const int z = blockIdx.z;
  const float* A = z == 0 ? Aq : z == 1 ? Ak : Av;
  const float* W = z == 0 ? Wq : z == 1 ? Wk : Wv;
  const float* bias = z == 0 ? bq : z == 1 ? bk : bv;
  const float wscale = z == 0 ? QSCALE * LOG2E : 1.0f;
  const float bscale = z == 0 ? LOG2E : 1.0f;
  const int tid = threadIdx.x;
  const int lane = tid & 63;
  const int wave = tid >> 6;
  const int quad = lane >> 4;
  const int l16 = lane & 15;
  const int m0b = blockIdx.x * 64;
  const int m0 = m0b + wave * 16;
  const int n0 = blockIdx.y * 64;

  stage_w(lds, W, n0, wscale, tid);
  __syncthreads();

  f32x4 acc[4];
#pragma unroll
  for (int i = 0; i < 4; ++i) acc[i] = f32x4{0.f, 0.f, 0.f, 0.f};
  const float* arow = A + (m0 + l16) * EMB;
#pragma unroll
  for (int k0 = 0; k0 < EMB; k0 += 32) {
    bf16x8 af = pack8(arow + k0 + quad * 8);
#pragma unroll
    for (int nt = 0; nt < 4; ++nt) {
      bf16x8 b = read_w(lds, nt * 16 + l16, k0, quad);
      acc[nt] = __builtin_amdgcn_mfma_f32_16x16x32_bf16(af, b, acc[nt], 0, 0, 0);
    }
  }
  __syncthreads();   // all waves done reading W tile; reuse lds as out-stage (stride 72)

#pragma unroll
  for (int nt = 0; nt < 4; ++nt) {
    float bn = bias[n0 + nt * 16 + l16] * bscale;
#pragma unroll
    for (int r = 0; r < 4; ++r)
      lds[(wave * 16 + quad * 4 + r) * 72 + nt * 16 + l16] = bfr(acc[nt][r] + bn);
  }
  __syncthreads();
  if (z < 2) {
    // coalesced 32B/thread stores to [bh][t][hd]; 16-col chunk stays inside one head
    int row = tid >> 2, seg = tid & 3;
    int m = m0b + row, t = m >> 2, b = m & 3;
    int n = n0 + seg * 16, h = n >> 5, hd = n & 31;
    unsigned short* dst = (z == 0 ? qh : kh) + (((b << 3) + h) * T_LEN + t) * HDIM + hd;
    *(bf16x8*)(dst + 0) = *(const bf16x8*)(lds + row * 72 + seg * 16 + 0);
    *(bf16x8*)(dst + 8) = *(const bf16x8*)(lds + row * 72 + seg * 16 + 8);
  } else {
    // transposed [bh][hd][t]: each thread emits one 32B t-contiguous chunk
    int n = tid >> 2, b = tid & 3;
    unsigned w[8];
#pragma unroll
    for (int i = 0; i < 8; ++i) {
      unsigned lo = lds[((2 * i) * 4 + b) * 72 + n];
      unsigned hi = lds[((2 * i + 1) * 4 + b) * 72 + n];
      w[i] = lo | (hi << 16);
    }
    int nf = n0 + n, h = nf >> 5, hd = nf & 31;
    int tbase = m0b >> 2;
    unsigned* base = (unsigned*)(vt + (((b << 3) + h) * HDIM + hd) * T_LEN + tbase);
    ((uint4*)base)[0] = make_uint4(w[0], w[1], w[2], w[3]);
    ((uint4*)base)[1] = make_uint4(w[4], w[5], w[6], w[7]);
  }
}

// out = A @ W^T + bias ; A bf16 [8192][256], W f32 staged->bf16 LDS, out fp32
__global__ __launch_bounds__(256) void out_gemm(const unsigned short* __restrict__ A,
                                                const float* __restrict__ W,
                                                const float* __restrict__ bias,
                                                float* __restrict__ out) {
  __shared__ __align__(16) unsigned short lds[64 * 256];   // 32 KB: W-tile, then f32 out-stage
  const int tid = threadIdx.x;
  const int lane = tid & 63;
  const int wave = tid >> 6;
  const int quad = lane >> 4;
  const int l16 = lane & 15;
  const int m0b = blockIdx.x * 64;
  const int m0 = m0b + wave * 16;
  const int n0 = blockIdx.y * 64;

  stage_w(lds, W, n0, 1.0f, tid);
  __syncthreads();

  f32x4 acc[4];
#pragma unroll
  for (int i = 0; i < 4; ++i) acc[i] = f32x4{0.f, 0.f, 0.f, 0.f};
  const unsigned short* arow = A + (m0 + l16) * EMB;
#pragma unroll
  for (int k0 = 0; k0 < EMB; k0 += 32) {
    bf16x8 af = *(const bf16x8*)(arow + k0 + quad * 8);
#pragma unroll
    for (int nt = 0; nt < 4; ++nt) {
      bf16x8 b = read_w(lds, nt * 16 + l16, k0, quad);
      acc[nt] = __builtin_amdgcn_mfma_f32_16x16x32_bf16(af, b, acc[nt], 0, 0, 0);
    }
  }
  __syncthreads();   // reuse lds as f32 out-stage (stride 68)

  float* fs = (float*)lds;
#pragma unroll
  for (int nt = 0; nt < 4; ++nt) {
    float bn = bias[n0 + nt * 16 + l16];
#pragma unroll
    for (int r = 0; r < 4; ++r)
      fs[(wave * 16 + quad * 4 + r) * 68 + nt * 16 + l16] = acc[nt][r] + bn;
  }
  __syncthreads();
  int row = tid >> 2, seg = tid & 3;
  const float4* srcp = (const float4*)(fs + row * 68 + seg * 16);
  float4* dstp = (float4*)(out + (m0b + row) * EMB + n0 + seg * 16);
#pragma unroll
  for (int i = 0; i < 4; ++i) dstp[i] = srcp[i];
}

// Flash attention: K+V LDS-staged (double-buffered 128-key chunks), 2 Q-frags
// per wave (32 q-rows). Hot loop per 16 keys: 1 ds_read_b128 (K) + 2 ds_read_b64
// (V) -> 2x S^T=K.Q^T (16x16x32) -> 8 exp2 (log2-domain, no max) -> 4 packs ->
// 4x 16x16x16 PV MFMA; denominator on VALU (6 adds) + cross-quad shfl reduce in
// epilogue; s_setprio(1) around MFMA clusters. (R10 body, unchanged.)
__global__ __launch_bounds__(256) void flash_attn(const unsigned short* __restrict__ qh,
                                                  const unsigned short* __restrict__ kh,
                                                  const unsigned short* __restrict__ vt,
                                                  unsigned short* __restrict__ aout) {
  __shared__ __align__(16) unsigned short kbuf[2][128 * 32];      // 2 x 8 KB, flat copy of K rows
  __shared__ __align__(16) unsigned short vbuf[2][32 * 136];      // 2 x 8.5 KB, V [d][key], stride 136
  const int tid = threadIdx.x;
  const int lane = tid & 63;
  const int wave = tid >> 6;
  const int quad = lane >> 4;
  const int l16 = lane & 15;
  const int bh = blockIdx.x;
  const int q0 = blockIdx.y * 128 + wave * 32;
  const unsigned short* qs = qh + bh * (T_LEN * HDIM);
  const unsigned short* ks = kh + bh * (T_LEN * HDIM);
  const unsigned short* vs = vt + bh * (T_LEN * HDIM);
  const bf16x8 qf0 = *(const bf16x8*)(qs + (q0 + l16) * HDIM + quad * 8);
  const bf16x8 qf1 = *(const bf16x8*)(qs + (q0 + 16 + l16) * HDIM + quad * 8);
  f32x4 o00 = {0.f, 0.f, 0.f, 0.f};
  f32x4 o01 = o00, o10 = o00, o11 = o00;
  float den0 = 0.f, den1 = 0.f;
  const f32x4 zero = o00;

  const int vrow = tid >> 4;          // 0..15 (and +16 in second shot)
  const int vcol = (tid & 15) * 8;    // 16B units along keys

  // stage chunk 0
  {
    uint4 ka = *(const uint4*)(ks + tid * 8);
    uint4 kb = *(const uint4*)(ks + (tid + 256) * 8);
    uint4 va = *(const uint4*)(vs + vrow * T_LEN + vcol);
    uint4 vb = *(const uint4*)(vs + (vrow + 16) * T_LEN + vcol);
    *(uint4*)(&kbuf[0][tid * 8]) = ka;
    *(uint4*)(&kbuf[0][(tid + 256) * 8]) = kb;
    *(uint4*)(&vbuf[0][vrow * 136 + vcol]) = va;
    *(uint4*)(&vbuf[0][(vrow + 16) * 136 + vcol]) = vb;
  }
  __syncthreads();

  for (int chunk = 0; chunk < 16; ++chunk) {
    const int buf = chunk & 1;
    uint4 ka, kb, va, vb;
    const bool pf = (chunk + 1) < 16;
    if (pf) {
      const int kk0 = (chunk + 1) * 128;
      const unsigned short* kg = ks + kk0 * HDIM;
      ka = *(const uint4*)(kg + tid * 8);
      kb = *(const uint4*)(kg + (tid + 256) * 8);
      va = *(const uint4*)(vs + vrow * T_LEN + kk0 + vcol);
      vb = *(const uint4*)(vs + (vrow + 16) * T_LEN + kk0 + vcol);
    }
#pragma unroll
    for (int it = 0; it < 8; ++it) {
      const int kkl = it * 16;
      bf16x8 kf = *(const bf16x8*)(&kbuf[buf][(kkl + l16) * 32 + quad * 8]);
      bf16x4 vfa = *(const bf16x4*)(&vbuf[buf][l16 * 136 + kkl + quad * 4]);
      bf16x4 vfb = *(const bf16x4*)(&vbuf[buf][(l16 + 16) * 136 + kkl + quad * 4]);
      __builtin_amdgcn_s_setprio(1);
      f32x4 s0 = __builtin_amdgcn_mfma_f32_16x16x32_bf16(kf, qf0, zero, 0, 0, 0);
      f32x4 s1 = __builtin_amdgcn_mfma_f32_16x16x32_bf16(kf, qf1, zero, 0, 0, 0);
      __builtin_amdgcn_s_setprio(0);
      union { unsigned u[2]; bf16x4 v; } pp0, pp1;
      {
        float a = __builtin_amdgcn_exp2f(s0[0]), b = __builtin_amdgcn_exp2f(s0[1]);
        float c = __builtin_amdgcn_exp2f(s0[2]), d = __builtin_amdgcn_exp2f(s0[3]);
        pp0.u[0] = pack2r(a, b); pp0.u[1] = pack2r(c, d);
        den0 += (a + b) + (c + d);
        a = __builtin_amdgcn_exp2f(s1[0]); b = __builtin_amdgcn_exp2f(s1[1]);
        c = __builtin_amdgcn_exp2f(s1[2]); d = __builtin_amdgcn_exp2f(s1[3]);
        pp1.u[0] = pack2r(a, b); pp1.u[1] = pack2r(c, d);
        den1 += (a + b) + (c + d);
      }
      __builtin_amdgcn_s_setprio(1);
      o00 = __builtin_amdgcn_mfma_f32_16x16x16bf16_1k(vfa, pp0.v, o00, 0, 0, 0);
      o01 = __builtin_amdgcn_mfma_f32_16x16x16bf16_1k(vfb, pp0.v, o01, 0, 0, 0);
      o10 = __builtin_amdgcn_mfma_f32_16x16x16bf16_1k(vfa, pp1.v, o10, 0, 0, 0);
      o11 = __builtin_amdgcn_mfma_f32_16x16x16bf16_1k(vfb, pp1.v, o11, 0, 0, 0);
      __builtin_amdgcn_s_setprio(0);
    }
    if (pf) {
      const int nb = buf ^ 1;
      *(uint4*)(&kbuf[nb][tid * 8]) = ka;
      *(uint4*)(&kbuf[nb][(tid + 256) * 8]) = kb;
      *(uint4*)(&vbuf[nb][vrow * 136 + vcol]) = va;
      *(uint4*)(&vbuf[nb][(vrow + 16) * 136 + vcol]) = vb;
    }
    __syncthreads();
  }

  // denominator: per-lane partial covers k = quad*4+{0..3} slices; full sum for
  // q=l16 is the reduction over the 4 quads (lane bits 4,5)
  float d0 = den0; d0 += __shfl_xor(d0, 16); d0 += __shfl_xor(d0, 32);
  float d1 = den1; d1 += __shfl_xor(d1, 16); d1 += __shfl_xor(d1, 32);

  // epilogue: normalize + O^T (C-layout: d=quad*4+r, q=l16) -> row-major [q][d]
  const int srcA = l16 + ((quad & 1) << 5);
  const int srcB = srcA + 16;
  const bool lowq = quad < 2;
  const int b = bh >> 3, h = bh & 7;
#pragma unroll
  for (int f = 0; f < 2; ++f) {
    f32x4 oh0 = f == 0 ? o00 : o10;
    f32x4 oh1 = f == 0 ? o01 : o11;
    const float inv = 1.f / (f == 0 ? d0 : d1);
    unsigned oa = pack2r(oh0[0] * inv, oh0[1] * inv), ob = pack2r(oh0[2] * inv, oh0[3] * inv);
    unsigned oc = pack2r(oh1[0] * inv, oh1[1] * inv), od = pack2r(oh1[2] * inv, oh1[3] * inv);
    union { unsigned u[4]; bf16x8 v; } of;
    unsigned ta, tc;
    ta = __shfl(oa, srcA); tc = __shfl(oc, srcA); of.u[0] = lowq ? ta : tc;
    ta = __shfl(ob, srcA); tc = __shfl(od, srcA); of.u[1] = lowq ? ta : tc;
    ta = __shfl(oa, srcB); tc = __shfl(oc, srcB); of.u[2] = lowq ? ta : tc;
    ta = __shfl(ob, srcB); tc = __shfl(od, srcB); of.u[3] = lowq ? ta : tc;
    const int t = q0 + f * 16 + l16;
    *(bf16x8*)(aout + (t * BSZ + b) * EMB + h * HDIM + quad * 8) = of.v;
  }
}

extern "C" void kernel_launch(void* const* d_in, const int* in_sizes, int n_in,
                              void* d_out, int out_size, void* d_ws, size_t ws_size,
                              hipStream_t stream) {
  const float* q  = (const float*)d_in[0];
  const float* k  = (const float*)d_in[1];
  const float* v  = (const float*)d_in[2];
  const float* Wq = (const float*)d_in[3];
  const float* bq = (const float*)d_in[4];
  const float* Wk = (const float*)d_in[5];
  const float* bk = (const float*)d_in[6];
  const float* Wv = (const float*)d_in[7];
  const float* bv = (const float*)d_in[8];
  const float* Wp = (const float*)d_in[9];
  const float* bp = (const float*)d_in[10];
  float* out = (float*)d_out;

  char* ws = (char*)d_ws;
  unsigned short* qh   = (unsigned short*)(ws);                    // 4 MiB
  unsigned short* kh   = (unsigned short*)(ws + (4u << 20));       // 4 MiB
  unsigned short* vt   = (unsigned short*)(ws + (8u << 20));       // 4 MiB
  unsigned short* aout = (unsigned short*)(ws + (12u << 20));      // 4 MiB

  qkv_proj<<<dim3(128, 4, 3), 256, 0, stream>>>(q, k, v, Wq, Wk, Wv, bq, bk, bv, qh, kh, vt);
  flash_attn<<<dim3(32, 16), 256, 0, stream>>>(qh, kh, vt, aout);
  out_gemm<<<dim3(128, 4), 256, 0, stream>>>(aout, Wp, bp, out);
}

// Round 7
// 140.467 us; speedup vs baseline: 1.3757x; 1.0382x over previous
//
#include <hip/hip_runtime.h>
#include <hip/hip_bf16.h>

#define T_LEN 2048
#define BSZ 4
#define EMB 256
#define HDIM 32
#define QSCALE 0.17677669529663687f
#define LOG2E 1.4426950408889634f

using bf16x8 = __attribute__((ext_vector_type(8))) short;
using bf16x4 = __attribute__((ext_vector_type(4))) short;
using f32x4 = __attribute__((ext_vector_type(4))) float;

static __device__ __forceinline__ unsigned fasu(float f) {
  union { float f; unsigned u; } c; c.f = f; return c.u;
}
// pack two floats to packed bf16 pair (round-half-up) in ONE v_perm + 2 adds
static __device__ __forceinline__ unsigned pack2r(float lo, float hi) {
  return __builtin_amdgcn_perm(fasu(hi) + 0x8000u, fasu(lo) + 0x8000u, 0x07060302u);
}
static __device__ __forceinline__ unsigned short bfr(float x) {
  return (unsigned short)((fasu(x) + 0x8000u) >> 16);
}
// build a bf16x8 MFMA fragment from 8 consecutive f32 (two float4 loads)
static __device__ __forceinline__ bf16x8 pack8(const float* __restrict__ p) {
  float4 w0 = ((const float4*)p)[0], w1 = ((const float4*)p)[1];
  union { unsigned u[4]; bf16x8 v; } f;
  f.u[0] = pack2r(w0.x, w0.y);
  f.u[1] = pack2r(w0.z, w0.w);
  f.u[2] = pack2r(w1.x, w1.y);
  f.u[3] = pack2r(w1.z, w1.w);
  return f.v;
}

// ---- cooperative W-tile stage: 64 rows x 256 k of f32 W -> swizzled bf16 LDS ----
// thread t: row r=t>>2, lane-quarter q4=t&3 covers k = q4*8 + c*32 (c=0..7).
// chunk index (16B units along k) = c*4+q4; stored at chunk^(r&7) -> 2-way max
// bank pattern on write AND on the hot-loop ds_read_b128 (free, m136).
static __device__ __forceinline__ void stage_w(unsigned short* __restrict__ lds,
                                               const float* __restrict__ W,
                                               int n0, float wscale, int tid) {
  const int r = tid >> 2, q4 = tid & 3;
  const float* wr = W + (n0 + r) * EMB + q4 * 8;
#pragma unroll
  for (int c = 0; c < 8; ++c) {
    float4 f0 = ((const float4*)(wr + c * 32))[0];
    float4 f1 = ((const float4*)(wr + c * 32))[1];
    union { unsigned u[4]; uint4 v; } pk;
    pk.u[0] = pack2r(f0.x * wscale, f0.y * wscale);
    pk.u[1] = pack2r(f0.z * wscale, f0.w * wscale);
    pk.u[2] = pack2r(f1.x * wscale, f1.y * wscale);
    pk.u[3] = pack2r(f1.z * wscale, f1.w * wscale);
    const int chunk = c * 4 + q4;
    *(uint4*)&lds[r * 256 + ((chunk ^ (r & 7)) << 3)] = pk.v;
  }
}
// swizzled fragment read: row, k0 (multiple of 32), quad
static __device__ __forceinline__ bf16x8 read_w(const unsigned short* __restrict__ lds,
                                                int row, int k0, int quad) {
  const int chunk = (k0 >> 3) + quad;
  return *(const bf16x8*)&lds[row * 256 + ((chunk ^ (row & 7)) << 3)];
}

// fused QKV projection: z=0 -> qh [bh][t][32], z=1 -> kh, z=2 -> vt [bh][32][t]
// W staged in LDS (R12), hot loop: 2 VMEM (A) + 4 ds_read_b128 + 4 MFMA per
// k-iter. Q scale folded into W pre-rounding. LDS reused for output stage.
__global__ __launch_bounds__(256) void qkv_proj(
    const float* __restrict__ Aq, const float* __restrict__ Ak, const float* __restrict__ Av,
    const float* __restrict__ Wq, const float* __restrict__ Wk, const float* __restrict__ Wv,
    const float* __restrict__ bq, const float* __restrict__ bk, const float* __restrict__ bv,
    unsigned short* __restrict__ qh, unsigned short* __restrict__ kh, unsigned short* __restrict__ vt) {
  __shared__ __align__(16) unsigned short lds[64 * 256];   // 32 KB: W-tile, then out-stage
  const int z = blockIdx.z;
  const float* A = z == 0 ? Aq : z == 1 ? Ak : Av;
  const float* W = z == 0 ? Wq : z == 1 ? Wk : Wv;
  const float* bias = z == 0 ? bq : z == 1 ? bk : bv;
  const float wscale = z == 0 ? QSCALE * LOG2E : 1.0f;
  const float bscale = z == 0 ? LOG2E : 1.0f;
  const int tid = threadIdx.x;
  const int lane = tid & 63;
  const int wave = tid >> 6;
  const int quad = lane >> 4;
  const int l16 = lane & 15;
  const int m0b = blockIdx.x * 64;
  const int m0 = m0b + wave * 16;
  const int n0 = blockIdx.y * 64;

  stage_w(lds, W, n0, wscale, tid);
  __syncthreads();

  f32x4 acc[4];
#pragma unroll
  for (int i = 0; i < 4; ++i) acc[i] = f32x4{0.f, 0.f, 0.f, 0.f};
  const float* arow = A + (m0 + l16) * EMB;
#pragma unroll
  for (int k0 = 0; k0 < EMB; k0 += 32) {
    bf16x8 af = pack8(arow + k0 + quad * 8);
#pragma unroll
    for (int nt = 0; nt < 4; ++nt) {
      bf16x8 b = read_w(lds, nt * 16 + l16, k0, quad);
      acc[nt] = __builtin_amdgcn_mfma_f32_16x16x32_bf16(af, b, acc[nt], 0, 0, 0);
    }
  }
  __syncthreads();   // all waves done reading W tile; reuse lds as out-stage (stride 72)

#pragma unroll
  for (int nt = 0; nt < 4; ++nt) {
    float bn = bias[n0 + nt * 16 + l16] * bscale;
#pragma unroll
    for (int r = 0; r < 4; ++r)
      lds[(wave * 16 + quad * 4 + r) * 72 + nt * 16 + l16] = bfr(acc[nt][r] + bn);
  }
  __syncthreads();
  if (z < 2) {
    // coalesced 32B/thread stores to [bh][t][hd]; 16-col chunk stays inside one head
    int row = tid >> 2, seg = tid & 3;
    int m = m0b + row, t = m >> 2, b = m & 3;
    int n = n0 + seg * 16, h = n >> 5, hd = n & 31;
    unsigned short* dst = (z == 0 ? qh : kh) + (((b << 3) + h) * T_LEN + t) * HDIM + hd;
    *(bf16x8*)(dst + 0) = *(const bf16x8*)(lds + row * 72 + seg * 16 + 0);
    *(bf16x8*)(dst + 8) = *(const bf16x8*)(lds + row * 72 + seg * 16 + 8);
  } else {
    // transposed [bh][hd][t]: each thread emits one 32B t-contiguous chunk
    int n = tid >> 2, b = tid & 3;
    unsigned w[8];
#pragma unroll
    for (int i = 0; i < 8; ++i) {
      unsigned lo = lds[((2 * i) * 4 + b) * 72 + n];
      unsigned hi = lds[((2 * i + 1) * 4 + b) * 72 + n];
      w[i] = lo | (hi << 16);
    }
    int nf = n0 + n, h = nf >> 5, hd = nf & 31;
    int tbase = m0b >> 2;
    unsigned* base = (unsigned*)(vt + (((b << 3) + h) * HDIM + hd) * T_LEN + tbase);
    ((uint4*)base)[0] = make_uint4(w[0], w[1], w[2], w[3]);
    ((uint4*)base)[1] = make_uint4(w[4], w[5], w[6], w[7]);
  }
}

// out = A @ W^T + bias ; A bf16 [8192][256], W f32 staged->bf16 LDS, out fp32
__global__ __launch_bounds__(256) void out_gemm(const unsigned short* __restrict__ A,
                                                const float* __restrict__ W,
                                                const float* __restrict__ bias,
                                                float* __restrict__ out) {
  __shared__ __align__(16) unsigned short lds[64 * 256];   // 32 KB: W-tile, then f32 out-stage
  const int tid = threadIdx.x;
  const int lane = tid & 63;
  const int wave = tid >> 6;
  const int quad = lane >> 4;
  const int l16 = lane & 15;
  const int m0b = blockIdx.x * 64;
  const int m0 = m0b + wave * 16;
  const int n0 = blockIdx.y * 64;

  stage_w(lds, W, n0, 1.0f, tid);
  __syncthreads();

  f32x4 acc[4];
#pragma unroll
  for (int i = 0; i < 4; ++i) acc[i] = f32x4{0.f, 0.f, 0.f, 0.f};
  const unsigned short* arow = A + (m0 + l16) * EMB;
#pragma unroll
  for (int k0 = 0; k0 < EMB; k0 += 32) {
    bf16x8 af = *(const bf16x8*)(arow + k0 + quad * 8);
#pragma unroll
    for (int nt = 0; nt < 4; ++nt) {
      bf16x8 b = read_w(lds, nt * 16 + l16, k0, quad);
      acc[nt] = __builtin_amdgcn_mfma_f32_16x16x32_bf16(af, b, acc[nt], 0, 0, 0);
    }
  }
  __syncthreads();   // reuse lds as f32 out-stage (stride 68)

  float* fs = (float*)lds;
#pragma unroll
  for (int nt = 0; nt < 4; ++nt) {
    float bn = bias[n0 + nt * 16 + l16];
#pragma unroll
    for (int r = 0; r < 4; ++r)
      fs[(wave * 16 + quad * 4 + r) * 68 + nt * 16 + l16] = acc[nt][r] + bn;
  }
  __syncthreads();
  int row = tid >> 2, seg = tid & 3;
  const float4* srcp = (const float4*)(fs + row * 68 + seg * 16);
  float4* dstp = (float4*)(out + (m0b + row) * EMB + n0 + seg * 16);
#pragma unroll
  for (int i = 0; i < 4; ++i) dstp[i] = srcp[i];
}

// Flash attention R13: 512 threads / 8 waves per block, ONE q-frag (16 rows)
// per wave (was 256 thr / 4 waves x 2 frags). Work-conserving TLP doubling:
// same grid (32,16), same LDS (33KB), same total staged bytes per block (each
// thread stages half as much), same MFMA/exp2 totals per SIMD -- but 4
// waves/SIMD instead of 2, so the serial QK->exp2->pack->PV chain of one wave
// hides under the other three. Hot loop per 16 keys per wave: 1 ds_read_b128
// (K) + 2 ds_read_b64 (V) -> S^T=K.Q^T (16x16x32) -> 4 exp2 -> 2 packs + 3
// den-adds (VALU) -> 2x 16x16x16 PV MFMA; s_setprio around MFMA.
__global__ __launch_bounds__(512) void flash_attn(const unsigned short* __restrict__ qh,
                                                  const unsigned short* __restrict__ kh,
                                                  const unsigned short* __restrict__ vt,
                                                  unsigned short* __restrict__ aout) {
  __shared__ __align__(16) unsigned short kbuf[2][128 * 32];      // 2 x 8 KB, flat copy of K rows
  __shared__ __align__(16) unsigned short vbuf[2][32 * 136];      // 2 x 8.5 KB, V [d][key], stride 136
  const int tid = threadIdx.x;
  const int lane = tid & 63;
  const int wave = tid >> 6;          // 0..7
  const int quad = lane >> 4;
  const int l16 = lane & 15;
  const int bh = blockIdx.x;
  const int q0 = blockIdx.y * 128 + wave * 16;
  const unsigned short* qs = qh + bh * (T_LEN * HDIM);
  const unsigned short* ks = kh + bh * (T_LEN * HDIM);
  const unsigned short* vs = vt + bh * (T_LEN * HDIM);
  const bf16x8 qf = *(const bf16x8*)(qs + (q0 + l16) * HDIM + quad * 8);
  f32x4 o0 = {0.f, 0.f, 0.f, 0.f};
  f32x4 o1 = o0;
  float den = 0.f;
  const f32x4 zero = o0;

  // staging split across 512 threads: K one uint4/thread (128 rows x 32),
  // V one uint4/thread (32 d-rows x 128 keys)
  const int vrow = tid >> 4;          // 0..31
  const int vcol = (tid & 15) * 8;    // 16B units along keys

  // stage chunk 0
  {
    uint4 ka = *(const uint4*)(ks + tid * 8);
    uint4 va = *(const uint4*)(vs + vrow * T_LEN + vcol);
    *(uint4*)(&kbuf[0][tid * 8]) = ka;
    *(uint4*)(&vbuf[0][vrow * 136 + vcol]) = va;
  }
  __syncthreads();

  for (int chunk = 0; chunk < 16; ++chunk) {
    const int buf = chunk & 1;
    uint4 ka, va;
    const bool pf = (chunk + 1) < 16;
    if (pf) {
      const int kk0 = (chunk + 1) * 128;
      ka = *(const uint4*)(ks + kk0 * HDIM + tid * 8);
      va = *(const uint4*)(vs + vrow * T_LEN + kk0 + vcol);
    }
#pragma unroll
    for (int it = 0; it < 8; ++it) {
      const int kkl = it * 16;
      bf16x8 kf = *(const bf16x8*)(&kbuf[buf][(kkl + l16) * 32 + quad * 8]);
      bf16x4 vfa = *(const bf16x4*)(&vbuf[buf][l16 * 136 + kkl + quad * 4]);
      bf16x4 vfb = *(const bf16x4*)(&vbuf[buf][(l16 + 16) * 136 + kkl + quad * 4]);
      __builtin_amdgcn_s_setprio(1);
      f32x4 s = __builtin_amdgcn_mfma_f32_16x16x32_bf16(kf, qf, zero, 0, 0, 0);
      __builtin_amdgcn_s_setprio(0);
      union { unsigned u[2]; bf16x4 v; } pp;
      {
        float a = __builtin_amdgcn_exp2f(s[0]), b = __builtin_amdgcn_exp2f(s[1]);
        float c = __builtin_amdgcn_exp2f(s[2]), d = __builtin_amdgcn_exp2f(s[3]);
        pp.u[0] = pack2r(a, b); pp.u[1] = pack2r(c, d);
        den += (a + b) + (c + d);
      }
      __builtin_amdgcn_s_setprio(1);
      o0 = __builtin_amdgcn_mfma_f32_16x16x16bf16_1k(vfa, pp.v, o0, 0, 0, 0);
      o1 = __builtin_amdgcn_mfma_f32_16x16x16bf16_1k(vfb, pp.v, o1, 0, 0, 0);
      __builtin_amdgcn_s_setprio(0);
    }
    if (pf) {
      const int nb = buf ^ 1;
      *(uint4*)(&kbuf[nb][tid * 8]) = ka;
      *(uint4*)(&vbuf[nb][vrow * 136 + vcol]) = va;
    }
    __syncthreads();
  }

  // denominator: per-lane partial covers k = quad*4+{0..3} slices; full sum for
  // q=l16 is the reduction over the 4 quads (lane bits 4,5)
  float d0 = den; d0 += __shfl_xor(d0, 16); d0 += __shfl_xor(d0, 32);

  // epilogue: normalize + O^T (C-layout: d=quad*4+r, q=l16) -> row-major [q][d]
  const int srcA = l16 + ((quad & 1) << 5);
  const int srcB = srcA + 16;
  const bool lowq = quad < 2;
  const int b = bh >> 3, h = bh & 7;
  {
    const float inv = 1.f / d0;
    unsigned oa = pack2r(o0[0] * inv, o0[1] * inv), ob = pack2r(o0[2] * inv, o0[3] * inv);
    unsigned oc = pack2r(o1[0] * inv, o1[1] * inv), od = pack2r(o1[2] * inv, o1[3] * inv);
    union { unsigned u[4]; bf16x8 v; } of;
    unsigned ta, tc;
    ta = __shfl(oa, srcA); tc = __shfl(oc, srcA); of.u[0] = lowq ? ta : tc;
    ta = __shfl(ob, srcA); tc = __shfl(od, srcA); of.u[1] = lowq ? ta : tc;
    ta = __shfl(oa, srcB); tc = __shfl(oc, srcB); of.u[2] = lowq ? ta : tc;
    ta = __shfl(ob, srcB); tc = __shfl(od, srcB); of.u[3] = lowq ? ta : tc;
    const int t = q0 + l16;
    *(bf16x8*)(aout + (t * BSZ + b) * EMB + h * HDIM + quad * 8) = of.v;
  }
}

extern "C" void kernel_launch(void* const* d_in, const int* in_sizes, int n_in,
                              void* d_out, int out_size, void* d_ws, size_t ws_size,
                              hipStream_t stream) {
  const float* q  = (const float*)d_in[0];
  const float* k  = (const float*)d_in[1];
  const float* v  = (const float*)d_in[2];
  const float* Wq = (const float*)d_in[3];
  const float* bq = (const float*)d_in[4];
  const float* Wk = (const float*)d_in[5];
  const float* bk = (const float*)d_in[6];
  const float* Wv = (const float*)d_in[7];
  const float* bv = (const float*)d_in[8];
  const float* Wp = (const float*)d_in[9];
  const float* bp = (const float*)d_in[10];
  float* out = (float*)d_out;

  char* ws = (char*)d_ws;
  unsigned short* qh   = (unsigned short*)(ws);                    // 4 MiB
  unsigned short* kh   = (unsigned short*)(ws + (4u << 20));       // 4 MiB
  unsigned short* vt   = (unsigned short*)(ws + (8u << 20));       // 4 MiB
  unsigned short* aout = (unsigned short*)(ws + (12u << 20));      // 4 MiB

  qkv_proj<<<dim3(128, 4, 3), 256, 0, stream>>>(q, k, v, Wq, Wk, Wv, bq, bk, bv, qh, kh, vt);
  flash_attn<<<dim3(32, 16), 512, 0, stream>>>(qh, kh, vt, aout);
  out_gemm<<<dim3(128, 4), 256, 0, stream>>>(aout, Wp, bp, out);
}

// Round 8
// 138.193 us; speedup vs baseline: 1.3984x; 1.0165x over previous
//
#include <hip/hip_runtime.h>
#include <hip/hip_bf16.h>

#define T_LEN 2048
#define BSZ 4
#define EMB 256
#define HDIM 32
#define QSCALE 0.17677669529663687f
#define LOG2E 1.4426950408889634f

using bf16x8 = __attribute__((ext_vector_type(8))) short;
using bf16x4 = __attribute__((ext_vector_type(4))) short;
using f32x4 = __attribute__((ext_vector_type(4))) float;

static __device__ __forceinline__ unsigned fasu(float f) {
  union { float f; unsigned u; } c; c.f = f; return c.u;
}
// pack two floats to packed bf16 pair (round-half-up) in ONE v_perm + 2 adds
static __device__ __forceinline__ unsigned pack2r(float lo, float hi) {
  return __builtin_amdgcn_perm(fasu(hi) + 0x8000u, fasu(lo) + 0x8000u, 0x07060302u);
}
static __device__ __forceinline__ unsigned short bfr(float x) {
  return (unsigned short)((fasu(x) + 0x8000u) >> 16);
}
// build a bf16x8 MFMA fragment from 8 consecutive f32 (two float4 loads)
static __device__ __forceinline__ bf16x8 pack8(const float* __restrict__ p) {
  float4 w0 = ((const float4*)p)[0], w1 = ((const float4*)p)[1];
  union { unsigned u[4]; bf16x8 v; } f;
  f.u[0] = pack2r(w0.x, w0.y);
  f.u[1] = pack2r(w0.z, w0.w);
  f.u[2] = pack2r(w1.x, w1.y);
  f.u[3] = pack2r(w1.z, w1.w);
  return f.v;
}

// ---- cooperative W-tile stage: 64 rows x 256 k of f32 W -> swizzled bf16 LDS ----
// thread t: row r=t>>2, lane-quarter q4=t&3 covers k = q4*8 + c*32 (c=0..7).
// chunk index (16B units along k) = c*4+q4; stored at chunk^(r&7) -> 2-way max
// bank pattern on write AND on the hot-loop ds_read_b128 (free, m136).
static __device__ __forceinline__ void stage_w(unsigned short* __restrict__ lds,
                                               const float* __restrict__ W,
                                               int n0, float wscale, int tid) {
  const int r = tid >> 2, q4 = tid & 3;
  const float* wr = W + (n0 + r) * EMB + q4 * 8;
#pragma unroll
  for (int c = 0; c < 8; ++c) {
    float4 f0 = ((const float4*)(wr + c * 32))[0];
    float4 f1 = ((const float4*)(wr + c * 32))[1];
    union { unsigned u[4]; uint4 v; } pk;
    pk.u[0] = pack2r(f0.x * wscale, f0.y * wscale);
    pk.u[1] = pack2r(f0.z * wscale, f0.w * wscale);
    pk.u[2] = pack2r(f1.x * wscale, f1.y * wscale);
    pk.u[3] = pack2r(f1.z * wscale, f1.w * wscale);
    const int chunk = c * 4 + q4;
    *(uint4*)&lds[r * 256 + ((chunk ^ (r & 7)) << 3)] = pk.v;
  }
}
// swizzled fragment read: row, k0 (multiple of 32), quad
static __device__ __forceinline__ bf16x8 read_w(const unsigned short* __restrict__ lds,
                                                int row, int k0, int quad) {
  const int chunk = (k0 >> 3) + quad;
  return *(const bf16x8*)&lds[row * 256 + ((chunk ^ (row & 7)) << 3)];
}

// fused QKV projection: z=0 -> qh [bh][t][32], z=1 -> kh, z=2 -> vt [bh][32][t]
// R14: m-tile 64->128 (grid 1536->768 blocks). Each block staged the same W
// n-tile that 128 sibling m-blocks also stage; doubling m-work per block
// halves stage_w overhead + W re-fetch per unit output. 2 m-frags/wave,
// acc[2][4], 8 MFMA per 4 ds_read. Epilogue loops 2x over the proven 64-row
// store paths. W staged in LDS (R12), Q scale folded into W pre-rounding.
__global__ __launch_bounds__(256) void qkv_proj(
    const float* __restrict__ Aq, const float* __restrict__ Ak, const float* __restrict__ Av,
    const float* __restrict__ Wq, const float* __restrict__ Wk, const float* __restrict__ Wv,
    const float* __restrict__ bq, const float* __restrict__ bk, const float* __restrict__ bv,
    unsigned short* __restrict__ qh, unsigned short* __restrict__ kh, unsigned short* __restrict__ vt) {
  __shared__ __align__(16) unsigned short lds[64 * 256];   // 32 KB: W-tile, then out-stage
  const int z = blockIdx.z;
  const float* A = z == 0 ? Aq : z == 1 ? Ak : Av;
  const float* W = z == 0 ? Wq : z == 1 ? Wk : Wv;
  const float* bias = z == 0 ? bq : z == 1 ? bk : bv;
  const float wscale = z == 0 ? QSCALE * LOG2E : 1.0f;
  const float bscale = z == 0 ? LOG2E : 1.0f;
  const int tid = threadIdx.x;
  const int lane = tid & 63;
  const int wave = tid >> 6;
  const int quad = lane >> 4;
  const int l16 = lane & 15;
  const int m0b = blockIdx.x * 128;
  const int m0 = m0b + wave * 16;
  const int n0 = blockIdx.y * 64;

  stage_w(lds, W, n0, wscale, tid);
  __syncthreads();

  f32x4 acc[2][4];
#pragma unroll
  for (int h = 0; h < 2; ++h)
#pragma unroll
    for (int i = 0; i < 4; ++i) acc[h][i] = f32x4{0.f, 0.f, 0.f, 0.f};
  const float* arow0 = A + (m0 + l16) * EMB;
  const float* arow1 = A + (m0 + 64 + l16) * EMB;
#pragma unroll
  for (int k0 = 0; k0 < EMB; k0 += 32) {
    bf16x8 a0 = pack8(arow0 + k0 + quad * 8);
    bf16x8 a1 = pack8(arow1 + k0 + quad * 8);
#pragma unroll
    for (int nt = 0; nt < 4; ++nt) {
      bf16x8 b = read_w(lds, nt * 16 + l16, k0, quad);
      acc[0][nt] = __builtin_amdgcn_mfma_f32_16x16x32_bf16(a0, b, acc[0][nt], 0, 0, 0);
      acc[1][nt] = __builtin_amdgcn_mfma_f32_16x16x32_bf16(a1, b, acc[1][nt], 0, 0, 0);
    }
  }
  __syncthreads();   // all waves done reading W tile; reuse lds as out-stage (stride 72)

  float bn[4];
#pragma unroll
  for (int nt = 0; nt < 4; ++nt) bn[nt] = bias[n0 + nt * 16 + l16] * bscale;

#pragma unroll
  for (int h = 0; h < 2; ++h) {
#pragma unroll
    for (int nt = 0; nt < 4; ++nt)
#pragma unroll
      for (int r = 0; r < 4; ++r)
        lds[(wave * 16 + quad * 4 + r) * 72 + nt * 16 + l16] = bfr(acc[h][nt][r] + bn[nt]);
    __syncthreads();
    if (z < 2) {
      // coalesced 32B/thread stores to [bh][t][hd]; 16-col chunk stays inside one head
      int row = tid >> 2, seg = tid & 3;
      int m = m0b + h * 64 + row, t = m >> 2, b = m & 3;
      int n = n0 + seg * 16, hh = n >> 5, hd = n & 31;
      unsigned short* dst = (z == 0 ? qh : kh) + (((b << 3) + hh) * T_LEN + t) * HDIM + hd;
      *(bf16x8*)(dst + 0) = *(const bf16x8*)(lds + row * 72 + seg * 16 + 0);
      *(bf16x8*)(dst + 8) = *(const bf16x8*)(lds + row * 72 + seg * 16 + 8);
    } else {
      // transposed [bh][hd][t]: each thread emits one 32B t-contiguous chunk
      int n = tid >> 2, b = tid & 3;
      unsigned w[8];
#pragma unroll
      for (int i = 0; i < 8; ++i) {
        unsigned lo = lds[((2 * i) * 4 + b) * 72 + n];
        unsigned hi = lds[((2 * i + 1) * 4 + b) * 72 + n];
        w[i] = lo | (hi << 16);
      }
      int nf = n0 + n, hh = nf >> 5, hd = nf & 31;
      int tbase = (m0b >> 2) + h * 16;
      unsigned* base = (unsigned*)(vt + (((b << 3) + hh) * HDIM + hd) * T_LEN + tbase);
      ((uint4*)base)[0] = make_uint4(w[0], w[1], w[2], w[3]);
      ((uint4*)base)[1] = make_uint4(w[4], w[5], w[6], w[7]);
    }
    if (h == 0) __syncthreads();   // protect stage buffer before half-1 overwrite
  }
}

// out = A @ W^T + bias ; A bf16 [8192][256], W f32 staged->bf16 LDS, out fp32
__global__ __launch_bounds__(256) void out_gemm(const unsigned short* __restrict__ A,
                                                const float* __restrict__ W,
                                                const float* __restrict__ bias,
                                                float* __restrict__ out) {
  __shared__ __align__(16) unsigned short lds[64 * 256];   // 32 KB: W-tile, then f32 out-stage
  const int tid = threadIdx.x;
  const int lane = tid & 63;
  const int wave = tid >> 6;
  const int quad = lane >> 4;
  const int l16 = lane & 15;
  const int m0b = blockIdx.x * 64;
  const int m0 = m0b + wave * 16;
  const int n0 = blockIdx.y * 64;

  stage_w(lds, W, n0, 1.0f, tid);
  __syncthreads();

  f32x4 acc[4];
#pragma unroll
  for (int i = 0; i < 4; ++i) acc[i] = f32x4{0.f, 0.f, 0.f, 0.f};
  const unsigned short* arow = A + (m0 + l16) * EMB;
#pragma unroll
  for (int k0 = 0; k0 < EMB; k0 += 32) {
    bf16x8 af = *(const bf16x8*)(arow + k0 + quad * 8);
#pragma unroll
    for (int nt = 0; nt < 4; ++nt) {
      bf16x8 b = read_w(lds, nt * 16 + l16, k0, quad);
      acc[nt] = __builtin_amdgcn_mfma_f32_16x16x32_bf16(af, b, acc[nt], 0, 0, 0);
    }
  }
  __syncthreads();   // reuse lds as f32 out-stage (stride 68)

  float* fs = (float*)lds;
#pragma unroll
  for (int nt = 0; nt < 4; ++nt) {
    float bn = bias[n0 + nt * 16 + l16];
#pragma unroll
    for (int r = 0; r < 4; ++r)
      fs[(wave * 16 + quad * 4 + r) * 68 + nt * 16 + l16] = acc[nt][r] + bn;
  }
  __syncthreads();
  int row = tid >> 2, seg = tid & 3;
  const float4* srcp = (const float4*)(fs + row * 68 + seg * 16);
  float4* dstp = (float4*)(out + (m0b + row) * EMB + n0 + seg * 16);
#pragma unroll
  for (int i = 0; i < 4; ++i) dstp[i] = srcp[i];
}

// Flash attention R13: 512 threads / 8 waves per block, ONE q-frag (16 rows)
// per wave. 4 waves/SIMD hide the serial QK->exp2->pack->PV chain. Within ~20%
// of its LDS-read floor (16 waves x 16KB/chunk @ 256B/clk/CU); q-rows/wave is
// the only remaining lever and it trades against this TLP. Hot loop per 16
// keys per wave: 1 ds_read_b128 (K, bank-even) + 2 ds_read_b64 (V) -> S^T=K.Q^T
// (16x16x32) -> 4 exp2 -> 2 packs + 3 den-adds -> 2x 16x16x16 PV MFMA.
__global__ __launch_bounds__(512) void flash_attn(const unsigned short* __restrict__ qh,
                                                  const unsigned short* __restrict__ kh,
                                                  const unsigned short* __restrict__ vt,
                                                  unsigned short* __restrict__ aout) {
  __shared__ __align__(16) unsigned short kbuf[2][128 * 32];      // 2 x 8 KB, flat copy of K rows
  __shared__ __align__(16) unsigned short vbuf[2][32 * 136];      // 2 x 8.5 KB, V [d][key], stride 136
  const int tid = threadIdx.x;
  const int lane = tid & 63;
  const int wave = tid >> 6;          // 0..7
  const int quad = lane >> 4;
  const int l16 = lane & 15;
  const int bh = blockIdx.x;
  const int q0 = blockIdx.y * 128 + wave * 16;
  const unsigned short* qs = qh + bh * (T_LEN * HDIM);
  const unsigned short* ks = kh + bh * (T_LEN * HDIM);
  const unsigned short* vs = vt + bh * (T_LEN * HDIM);
  const bf16x8 qf = *(const bf16x8*)(qs + (q0 + l16) * HDIM + quad * 8);
  f32x4 o0 = {0.f, 0.f, 0.f, 0.f};
  f32x4 o1 = o0;
  float den = 0.f;
  const f32x4 zero = o0;

  // staging split across 512 threads: K one uint4/thread (128 rows x 32),
  // V one uint4/thread (32 d-rows x 128 keys)
  const int vrow = tid >> 4;          // 0..31
  const int vcol = (tid & 15) * 8;    // 16B units along keys

  // stage chunk 0
  {
    uint4 ka = *(const uint4*)(ks + tid * 8);
    uint4 va = *(const uint4*)(vs + vrow * T_LEN + vcol);
    *(uint4*)(&kbuf[0][tid * 8]) = ka;
    *(uint4*)(&vbuf[0][vrow * 136 + vcol]) = va;
  }
  __syncthreads();

  for (int chunk = 0; chunk < 16; ++chunk) {
    const int buf = chunk & 1;
    uint4 ka, va;
    const bool pf = (chunk + 1) < 16;
    if (pf) {
      const int kk0 = (chunk + 1) * 128;
      ka = *(const uint4*)(ks + kk0 * HDIM + tid * 8);
      va = *(const uint4*)(vs + vrow * T_LEN + kk0 + vcol);
    }
#pragma unroll
    for (int it = 0; it < 8; ++it) {
      const int kkl = it * 16;
      bf16x8 kf = *(const bf16x8*)(&kbuf[buf][(kkl + l16) * 32 + quad * 8]);
      bf16x4 vfa = *(const bf16x4*)(&vbuf[buf][l16 * 136 + kkl + quad * 4]);
      bf16x4 vfb = *(const bf16x4*)(&vbuf[buf][(l16 + 16) * 136 + kkl + quad * 4]);
      __builtin_amdgcn_s_setprio(1);
      f32x4 s = __builtin_amdgcn_mfma_f32_16x16x32_bf16(kf, qf, zero, 0, 0, 0);
      __builtin_amdgcn_s_setprio(0);
      union { unsigned u[2]; bf16x4 v; } pp;
      {
        float a = __builtin_amdgcn_exp2f(s[0]), b = __builtin_amdgcn_exp2f(s[1]);
        float c = __builtin_amdgcn_exp2f(s[2]), d = __builtin_amdgcn_exp2f(s[3]);
        pp.u[0] = pack2r(a, b); pp.u[1] = pack2r(c, d);
        den += (a + b) + (c + d);
      }
      __builtin_amdgcn_s_setprio(1);
      o0 = __builtin_amdgcn_mfma_f32_16x16x16bf16_1k(vfa, pp.v, o0, 0, 0, 0);
      o1 = __builtin_amdgcn_mfma_f32_16x16x16bf16_1k(vfb, pp.v, o1, 0, 0, 0);
      __builtin_amdgcn_s_setprio(0);
    }
    if (pf) {
      const int nb = buf ^ 1;
      *(uint4*)(&kbuf[nb][tid * 8]) = ka;
      *(uint4*)(&vbuf[nb][vrow * 136 + vcol]) = va;
    }
    __syncthreads();
  }

  // denominator: per-lane partial covers k = quad*4+{0..3} slices; full sum for
  // q=l16 is the reduction over the 4 quads (lane bits 4,5)
  float d0 = den; d0 += __shfl_xor(d0, 16); d0 += __shfl_xor(d0, 32);

  // epilogue: normalize + O^T (C-layout: d=quad*4+r, q=l16) -> row-major [q][d]
  const int srcA = l16 + ((quad & 1) << 5);
  const int srcB = srcA + 16;
  const bool lowq = quad < 2;
  const int b = bh >> 3, h = bh & 7;
  {
    const float inv = 1.f / d0;
    unsigned oa = pack2r(o0[0] * inv, o0[1] * inv), ob = pack2r(o0[2] * inv, o0[3] * inv);
    unsigned oc = pack2r(o1[0] * inv, o1[1] * inv), od = pack2r(o1[2] * inv, o1[3] * inv);
    union { unsigned u[4]; bf16x8 v; } of;
    unsigned ta, tc;
    ta = __shfl(oa, srcA); tc = __shfl(oc, srcA); of.u[0] = lowq ? ta : tc;
    ta = __shfl(ob, srcA); tc = __shfl(od, srcA); of.u[1] = lowq ? ta : tc;
    ta = __shfl(oa, srcB); tc = __shfl(oc, srcB); of.u[2] = lowq ? ta : tc;
    ta = __shfl(ob, srcB); tc = __shfl(od, srcB); of.u[3] = lowq ? ta : tc;
    const int t = q0 + l16;
    *(bf16x8*)(aout + (t * BSZ + b) * EMB + h * HDIM + quad * 8) = of.v;
  }
}

extern "C" void kernel_launch(void* const* d_in, const int* in_sizes, int n_in,
                              void* d_out, int out_size, void* d_ws, size_t ws_size,
                              hipStream_t stream) {
  const float* q  = (const float*)d_in[0];
  const float* k  = (const float*)d_in[1];
  const float* v  = (const float*)d_in[2];
  const float* Wq = (const float*)d_in[3];
  const float* bq = (const float*)d_in[4];
  const float* Wk = (const float*)d_in[5];
  const float* bk = (const float*)d_in[6];
  const float* Wv = (const float*)d_in[7];
  const float* bv = (const float*)d_in[8];
  const float* Wp = (const float*)d_in[9];
  const float* bp = (const float*)d_in[10];
  float* out = (float*)d_out;

  char* ws = (char*)d_ws;
  unsigned short* qh   = (unsigned short*)(ws);                    // 4 MiB
  unsigned short* kh   = (unsigned short*)(ws + (4u << 20));       // 4 MiB
  unsigned short* vt   = (unsigned short*)(ws + (8u << 20));       // 4 MiB
  unsigned short* aout = (unsigned short*)(ws + (12u << 20));      // 4 MiB

  qkv_proj<<<dim3(64, 4, 3), 256, 0, stream>>>(q, k, v, Wq, Wk, Wv, bq, bk, bv, qh, kh, vt);
  flash_attn<<<dim3(32, 16), 512, 0, stream>>>(qh, kh, vt, aout);
  out_gemm<<<dim3(128, 4), 256, 0, stream>>>(aout, Wp, bp, out);
}